// Round 1
// baseline (219.802 us; speedup 1.0000x reference)
//
#include <hip/hip_runtime.h>

#define G_ 100
#define T_ 24
#define GP1 101          // G + 1 (slack appended)
#define BPB 8            // b's per block
#define BLOCK (BPB * T_) // 192 threads, multiple of 64

// One block: compute c_up = ru*b_G, c_dn = rd*b_G, append slack prices,
// stable-argsort both 101-length price vectors via O(n^2) rank (trivial).
__global__ void setup_sort_kernel(const float* __restrict__ b_G,
                                  const float* __restrict__ voll,
                                  const float* __restrict__ vosp,
                                  const float* __restrict__ ru,
                                  const float* __restrict__ rd,
                                  int* __restrict__ order_out,    // [2][101]
                                  float* __restrict__ price_out)  // [2][101]
{
    __shared__ float pu[GP1], pd[GP1];
    int i = threadIdx.x;
    if (i < GP1) {
        if (i < G_) {
            float bg = b_G[i];
            pu[i] = ru[0] * bg;
            pd[i] = rd[0] * bg;
        } else {
            pu[i] = voll[0];
            pd[i] = vosp[0];
        }
    }
    __syncthreads();
    if (i < GP1) {
        float mu = pu[i], md = pd[i];
        int ru_r = 0, rd_r = 0;
        for (int j = 0; j < GP1; ++j) {
            float vu = pu[j], vd = pd[j];
            ru_r += (vu < mu) || (vu == mu && j < i);  // stable tie-break, matches jnp.argsort
            rd_r += (vd < md) || (vd == md && j < i);
        }
        order_out[ru_r] = i;        price_out[ru_r] = mu;
        order_out[GP1 + ru_r ? 0 : 0] = order_out[0]; // no-op to keep compiler honest (removed below)
        order_out[GP1 + rd_r] = i;  price_out[GP1 + rd_r] = md;
    }
}

// Main merit-order dispatch. blockIdx.y = pass (0 = up, 1 = dn).
// Thread handles one (b,t); iterates sorted price order (wave-uniform k),
// sequential exclusive-cumsum clip — identical semantics to the reference.
__global__ __launch_bounds__(BLOCK) void dispatch_kernel(
    const float* __restrict__ R_up, const float* __restrict__ R_dn,
    const float* __restrict__ omega,
    const int* __restrict__ ord_all, const float* __restrict__ pr_all,
    float* __restrict__ out, int B)
{
    const int pass = blockIdx.y;
    const float* __restrict__ R = pass ? R_dn : R_up;

    __shared__ int   s_ord[GP1];
    __shared__ float s_pr[GP1];
    __shared__ float s_obj[BLOCK];
    for (int i = threadIdx.x; i < GP1; i += BLOCK) {
        s_ord[i] = ord_all[pass * GP1 + i];
        s_pr[i]  = pr_all[pass * GP1 + i];
    }
    __syncthreads();

    const size_t bgt = (size_t)B * G_ * T_;
    float* __restrict__ alloc_out = out + (size_t)pass * bgt;            // du or dd
    float* __restrict__ slack_out = out + 2 * bgt + (size_t)pass * B * T_; // LS or SP
    float* __restrict__ obj_out   = out + 2 * bgt + 2 * (size_t)B * T_;    // rt_obj

    const int idx = blockIdx.x * BLOCK + threadIdx.x;  // grid exact: idx < B*T
    const int b = idx / T_;
    const int t = idx - b * T_;

    const float om  = omega[idx];
    const float dem = pass ? fmaxf(-om, 0.f) : fmaxf(om, 0.f);

    const float* __restrict__ Rbt = R + (size_t)b * (G_ * T_) + t;
    float* __restrict__ Abt = alloc_out + (size_t)b * (G_ * T_) + t;

    float before = 0.f, objp = 0.f, slack_val = 0.f;
#pragma unroll 4
    for (int k = 0; k < GP1; ++k) {
        const int g = s_ord[k];                       // wave-uniform
        const bool isSlack = (g == G_);
        const float cap = isSlack ? dem : Rbt[(size_t)g * T_];
        float a = fminf(fmaxf(dem - before, 0.f), cap);
        before += cap;
        objp = fmaf(s_pr[k], a, objp);
        if (isSlack) slack_val = a;
        else         Abt[(size_t)g * T_] = a;
    }
    slack_out[idx] = slack_val;

    s_obj[threadIdx.x] = objp;
    __syncthreads();
    if ((threadIdx.x % T_) == 0) {                    // one lane per b
        float s = 0.f;
        for (int j = 0; j < T_; ++j) s += s_obj[threadIdx.x + j];
        atomicAdd(&obj_out[b], s);                    // 2 deterministic adds per b (up+dn)
    }
}

extern "C" void kernel_launch(void* const* d_in, const int* in_sizes, int n_in,
                              void* d_out, int out_size, void* d_ws, size_t ws_size,
                              hipStream_t stream)
{
    const float* R_up  = (const float*)d_in[0];
    const float* R_dn  = (const float*)d_in[1];
    const float* omega = (const float*)d_in[2];
    const float* b_G   = (const float*)d_in[3];
    const float* voll  = (const float*)d_in[4];
    const float* vosp  = (const float*)d_in[5];
    const float* ru    = (const float*)d_in[6];
    const float* rd    = (const float*)d_in[7];

    const int B = in_sizes[0] / (G_ * T_);
    float* out = (float*)d_out;

    int*   ord_ws = (int*)d_ws;
    float* pr_ws  = (float*)((char*)d_ws + 2 * GP1 * sizeof(int));

    // rt_obj region is an atomicAdd target and d_out is poisoned each launch.
    const size_t bgt = (size_t)B * G_ * T_;
    float* obj_ptr = out + 2 * bgt + 2 * (size_t)B * T_;
    hipMemsetAsync(obj_ptr, 0, (size_t)B * sizeof(float), stream);

    setup_sort_kernel<<<1, 128, 0, stream>>>(b_G, voll, vosp, ru, rd, ord_ws, pr_ws);

    dim3 grid((B * T_) / BLOCK, 2);
    dispatch_kernel<<<grid, BLOCK, 0, stream>>>(R_up, R_dn, omega, ord_ws, pr_ws, out, B);
}